// Round 1
// baseline (281.315 us; speedup 1.0000x reference)
//
#include <hip/hip_runtime.h>

// Recall over [B=32, F=512, T=2048]:
//   p_adj[b,f,t] = predicted[b, f==0?1:f, t==0?1:t]
//   out = sum(p_adj * (gt!=0)) / count(gt!=0), or 0 if count==0.
//
// R10: drop nontemporal load hints. Rationale: inputs (256 MiB total) are
// restored (written) immediately before the timed kernel, so they should be
// Infinity-Cache (L3, 256 MiB) resident at kernel start. For a read-once
// stream, nt cannot help (reads don't allocate in a memory-side cache) and
// may forfeit L3 hits if the nt flag downgrades the LLC path. Also split
// the accumulator into 4 independent chains (removes 64-deep serial fadd
// dependency). Structure otherwise identical to R9: fused edge correction
// (40 scattered items/block), descending block->data mapping, 2048 blocks
// x 256 thr = 8 blocks/CU = 32 waves/CU, block covers contiguous 64KB per
// array, single resident round.

constexpr int B_ = 32;
constexpr int F_ = 512;
constexpr int T_ = 2048;
constexpr long long NTOT = (long long)B_ * F_ * T_;   // 2^25
constexpr int NQ      = (int)(NTOT >> 2);             // 8,388,608 quads
constexpr int BLK     = 256;
constexpr int NBLK    = 2048;                         // 8 blocks/CU, 1 round
constexpr int QPB     = NQ / NBLK;                    // 4096 quads per block
constexpr int QPW     = QPB / 4;                      // 1024 quads per wave
constexpr int PER_THR = QPW / 64;                     // 16 quads per thread
static_assert((long long)NBLK * QPB == NQ, "exact cover");

constexpr int EDGE_ITEMS   = B_ * T_ + B_ * F_;       // 81,920
constexpr int EDGE_PER_BLK = EDGE_ITEMS / NBLK;       // 40
static_assert(EDGE_PER_BLK * NBLK == EDGE_ITEMS, "exact edge cover");

typedef float vf4 __attribute__((ext_vector_type(4)));
typedef int   vi4 __attribute__((ext_vector_type(4)));

// ---------------- block reduction helper ----------------
__device__ __forceinline__ void block_reduce(float& s, int& c) {
    #pragma unroll
    for (int off = 32; off > 0; off >>= 1) {
        s += __shfl_down(s, off, 64);
        c += __shfl_down(c, off, 64);
    }
    __shared__ float ss[4];
    __shared__ int   sc[4];
    int lane = threadIdx.x & 63, wave = threadIdx.x >> 6;
    if (lane == 0) { ss[wave] = s; sc[wave] = c; }
    __syncthreads();
    if (threadIdx.x == 0) {
        s = ss[0] + ss[1] + ss[2] + ss[3];
        c = sc[0] + sc[1] + sc[2] + sc[3];
    }
}

// ---------------- main: streaming masked sum + fused edge correction ------
__global__ __launch_bounds__(256) void recall_main(
    const float* __restrict__ pred,
    const int* __restrict__ gt,
    float* __restrict__ bsum,
    unsigned int* __restrict__ bcnt)
{
    const unsigned lane = threadIdx.x & 63;
    const unsigned wave = threadIdx.x >> 6;
    // Descending data mapping: block 0 reads the highest addresses (written
    // most recently by the harness restore/poison) first.
    const unsigned db = (unsigned)(NBLK - 1) - blockIdx.x;
    const size_t base = (size_t)db * QPB + (size_t)wave * QPW + lane;

    const vf4* p4 = (const vf4*)pred;
    const vi4* g4 = (const vi4*)gt;

    float s0 = 0.f, s1 = 0.f, s2 = 0.f, s3 = 0.f;
    int   c0 = 0, c1 = 0, c2 = 0, c3 = 0;

    // Fused edge-remap correction: 40 items per block, threads 0..39.
    //   item < B*T:          f==0 row (b,t): remap f->1, t->max(t,1)
    //   item >= B*T:         t==0 col, f>=1: remap t->1 (f==0,t==0 already
    //                        covered by the first range)
    // corr = p[adj] - p[raw] at gt-nonzero positions; count is unchanged.
    if (threadIdx.x < EDGE_PER_BLK) {
        unsigned idx = blockIdx.x * EDGE_PER_BLK + threadIdx.x;
        if (idx < (unsigned)(B_ * T_)) {
            unsigned b = idx >> 11, t = idx & (T_ - 1);
            unsigned raw = (b << 20) | t;
            unsigned tp  = (t == 0u) ? 1u : t;
            unsigned adj = (b << 20) | (1u << 11) | tp;
            if (gt[raw]) s0 += pred[adj] - pred[raw];
        } else {
            unsigned i2 = idx - (unsigned)(B_ * T_);
            unsigned b = i2 >> 9, f = i2 & (F_ - 1);
            if (f != 0u) {
                unsigned raw = (b << 20) | (f << 11);
                if (gt[raw]) s0 += pred[raw + 1] - pred[raw];
            }
        }
    }

    // Streaming masked sum over this block's contiguous 64KB/array chunk.
    // Plain (cached) loads: inputs were just written by the harness restore,
    // so they are L3-resident; let the LLC serve them.
    #pragma unroll
    for (int k = 0; k < PER_THR; ++k) {
        size_t q = base + (size_t)k * 64;
        vf4 p = p4[q];
        vi4 g = g4[q];
        c0 += (g.x != 0);
        c1 += (g.y != 0);
        c2 += (g.z != 0);
        c3 += (g.w != 0);
        s0 += (g.x ? p.x : 0.f);
        s1 += (g.y ? p.y : 0.f);
        s2 += (g.z ? p.z : 0.f);
        s3 += (g.w ? p.w : 0.f);
    }

    float lsum = (s0 + s1) + (s2 + s3);
    int   lcnt = (c0 + c1) + (c2 + c3);

    block_reduce(lsum, lcnt);
    if (threadIdx.x == 0) {
        bsum[blockIdx.x] = lsum;
        bcnt[blockIdx.x] = (unsigned int)lcnt;
    }
}

// ---------------- finalize ----------------
__global__ __launch_bounds__(256) void recall_fin(
    const float* __restrict__ bsum,
    const unsigned int* __restrict__ bcnt,
    float* __restrict__ out)
{
    float s = 0.f;
    int   c = 0;
    for (int j = threadIdx.x; j < NBLK; j += BLK) {
        s += bsum[j];
        c += (int)bcnt[j];
    }
    block_reduce(s, c);
    if (threadIdx.x == 0)
        out[0] = (c > 0) ? (s / (float)c) : 0.0f;
}

extern "C" void kernel_launch(void* const* d_in, const int* in_sizes, int n_in,
                              void* d_out, int out_size, void* d_ws, size_t ws_size,
                              hipStream_t stream)
{
    const float* pred = (const float*)d_in[0];
    const int*   gt   = (const int*)d_in[1];
    float*       out  = (float*)d_out;

    float*        bsum = (float*)d_ws;
    unsigned int* bcnt = (unsigned int*)((char*)d_ws + NBLK * sizeof(float));

    recall_main<<<NBLK, BLK, 0, stream>>>(pred, gt, bsum, bcnt);
    recall_fin<<<1, BLK, 0, stream>>>(bsum, bcnt, out);
}

// Round 2
// 251.697 us; speedup vs baseline: 1.1177x; 1.1177x over previous
//
#include <hip/hip_runtime.h>

// Recall over [B=32, F=512, T=2048]:
//   p_adj[b,f,t] = predicted[b, f==0?1:f, t==0?1:t]
//   out = sum(p_adj * (gt!=0)) / count(gt!=0), or 0 if count==0.
//
// R11: revert R10's cached-load experiment (it regressed: plain loads were
// latency-bound at 2.7 TB/s even with ~50% L3 hits; nt streaming was
// faster) and deepen the memory pipeline: batch 4 iterations (8 nt
// dwordx4 loads in flight per batch) before consuming, lifting in-flight
// bytes per wave ~4x. VGPR grows ~32 -> ~64, still 8 waves/SIMD.
// Structure kept from R9: fused edge correction (40 scattered items per
// block), descending block->data mapping, 2048 blocks x 256 thr =
// 8 blocks/CU = 32 waves/CU, block covers contiguous 64KB per array,
// single resident round.

constexpr int B_ = 32;
constexpr int F_ = 512;
constexpr int T_ = 2048;
constexpr long long NTOT = (long long)B_ * F_ * T_;   // 2^25
constexpr int NQ      = (int)(NTOT >> 2);             // 8,388,608 quads
constexpr int BLK     = 256;
constexpr int NBLK    = 2048;                         // 8 blocks/CU, 1 round
constexpr int QPB     = NQ / NBLK;                    // 4096 quads per block
constexpr int QPW     = QPB / 4;                      // 1024 quads per wave
constexpr int PER_THR = QPW / 64;                     // 16 quads per thread
static_assert((long long)NBLK * QPB == NQ, "exact cover");

constexpr int EDGE_ITEMS   = B_ * T_ + B_ * F_;       // 81,920
constexpr int EDGE_PER_BLK = EDGE_ITEMS / NBLK;       // 40
static_assert(EDGE_PER_BLK * NBLK == EDGE_ITEMS, "exact edge cover");

typedef float vf4 __attribute__((ext_vector_type(4)));
typedef int   vi4 __attribute__((ext_vector_type(4)));

// ---------------- block reduction helper ----------------
__device__ __forceinline__ void block_reduce(float& s, int& c) {
    #pragma unroll
    for (int off = 32; off > 0; off >>= 1) {
        s += __shfl_down(s, off, 64);
        c += __shfl_down(c, off, 64);
    }
    __shared__ float ss[4];
    __shared__ int   sc[4];
    int lane = threadIdx.x & 63, wave = threadIdx.x >> 6;
    if (lane == 0) { ss[wave] = s; sc[wave] = c; }
    __syncthreads();
    if (threadIdx.x == 0) {
        s = ss[0] + ss[1] + ss[2] + ss[3];
        c = sc[0] + sc[1] + sc[2] + sc[3];
    }
}

// ---------------- main: streaming masked sum + fused edge correction ------
__global__ __launch_bounds__(256) void recall_main(
    const float* __restrict__ pred,
    const int* __restrict__ gt,
    float* __restrict__ bsum,
    unsigned int* __restrict__ bcnt)
{
    const unsigned lane = threadIdx.x & 63;
    const unsigned wave = threadIdx.x >> 6;
    // Descending data mapping: block 0 reads the highest addresses (written
    // most recently by the harness restore/poison) first.
    const unsigned db = (unsigned)(NBLK - 1) - blockIdx.x;
    const size_t base = (size_t)db * QPB + (size_t)wave * QPW + lane;

    const vf4* p4 = (const vf4*)pred;
    const vi4* g4 = (const vi4*)gt;

    float s0 = 0.f, s1 = 0.f, s2 = 0.f, s3 = 0.f;
    int   c0 = 0, c1 = 0, c2 = 0, c3 = 0;

    // Fused edge-remap correction: 40 items per block, threads 0..39.
    //   item < B*T:          f==0 row (b,t): remap f->1, t->max(t,1)
    //   item >= B*T:         t==0 col, f>=1: remap t->1 (f==0,t==0 already
    //                        covered by the first range)
    // corr = p[adj] - p[raw] at gt-nonzero positions; count is unchanged.
    if (threadIdx.x < EDGE_PER_BLK) {
        unsigned idx = blockIdx.x * EDGE_PER_BLK + threadIdx.x;
        if (idx < (unsigned)(B_ * T_)) {
            unsigned b = idx >> 11, t = idx & (T_ - 1);
            unsigned raw = (b << 20) | t;
            unsigned tp  = (t == 0u) ? 1u : t;
            unsigned adj = (b << 20) | (1u << 11) | tp;
            if (gt[raw]) s0 += pred[adj] - pred[raw];
        } else {
            unsigned i2 = idx - (unsigned)(B_ * T_);
            unsigned b = i2 >> 9, f = i2 & (F_ - 1);
            if (f != 0u) {
                unsigned raw = (b << 20) | (f << 11);
                if (gt[raw]) s0 += pred[raw + 1] - pred[raw];
            }
        }
    }

    // Streaming masked sum over this block's contiguous 64KB/array chunk.
    // nt loads (proven faster than cached in R10's A/B) + 4-deep batching:
    // 8 independent dwordx4 loads issued before any consumption, so each
    // wave keeps ~8 KB in flight instead of ~2 KB.
    #pragma unroll
    for (int k = 0; k < PER_THR; k += 4) {
        const size_t q0 = base + (size_t)(k + 0) * 64;
        const size_t q1 = base + (size_t)(k + 1) * 64;
        const size_t q2 = base + (size_t)(k + 2) * 64;
        const size_t q3 = base + (size_t)(k + 3) * 64;
        vf4 p0 = __builtin_nontemporal_load(&p4[q0]);
        vf4 p1 = __builtin_nontemporal_load(&p4[q1]);
        vf4 p2 = __builtin_nontemporal_load(&p4[q2]);
        vf4 p3 = __builtin_nontemporal_load(&p4[q3]);
        vi4 g0 = __builtin_nontemporal_load(&g4[q0]);
        vi4 g1 = __builtin_nontemporal_load(&g4[q1]);
        vi4 g2 = __builtin_nontemporal_load(&g4[q2]);
        vi4 g3 = __builtin_nontemporal_load(&g4[q3]);

        c0 += (g0.x != 0) + (g1.x != 0) + (g2.x != 0) + (g3.x != 0);
        c1 += (g0.y != 0) + (g1.y != 0) + (g2.y != 0) + (g3.y != 0);
        c2 += (g0.z != 0) + (g1.z != 0) + (g2.z != 0) + (g3.z != 0);
        c3 += (g0.w != 0) + (g1.w != 0) + (g2.w != 0) + (g3.w != 0);

        s0 += (g0.x ? p0.x : 0.f);
        s1 += (g0.y ? p0.y : 0.f);
        s2 += (g0.z ? p0.z : 0.f);
        s3 += (g0.w ? p0.w : 0.f);
        s0 += (g1.x ? p1.x : 0.f);
        s1 += (g1.y ? p1.y : 0.f);
        s2 += (g1.z ? p1.z : 0.f);
        s3 += (g1.w ? p1.w : 0.f);
        s0 += (g2.x ? p2.x : 0.f);
        s1 += (g2.y ? p2.y : 0.f);
        s2 += (g2.z ? p2.z : 0.f);
        s3 += (g2.w ? p2.w : 0.f);
        s0 += (g3.x ? p3.x : 0.f);
        s1 += (g3.y ? p3.y : 0.f);
        s2 += (g3.z ? p3.z : 0.f);
        s3 += (g3.w ? p3.w : 0.f);
    }

    float lsum = (s0 + s1) + (s2 + s3);
    int   lcnt = (c0 + c1) + (c2 + c3);

    block_reduce(lsum, lcnt);
    if (threadIdx.x == 0) {
        bsum[blockIdx.x] = lsum;
        bcnt[blockIdx.x] = (unsigned int)lcnt;
    }
}

// ---------------- finalize ----------------
__global__ __launch_bounds__(256) void recall_fin(
    const float* __restrict__ bsum,
    const unsigned int* __restrict__ bcnt,
    float* __restrict__ out)
{
    float s = 0.f;
    int   c = 0;
    for (int j = threadIdx.x; j < NBLK; j += BLK) {
        s += bsum[j];
        c += (int)bcnt[j];
    }
    block_reduce(s, c);
    if (threadIdx.x == 0)
        out[0] = (c > 0) ? (s / (float)c) : 0.0f;
}

extern "C" void kernel_launch(void* const* d_in, const int* in_sizes, int n_in,
                              void* d_out, int out_size, void* d_ws, size_t ws_size,
                              hipStream_t stream)
{
    const float* pred = (const float*)d_in[0];
    const int*   gt   = (const int*)d_in[1];
    float*       out  = (float*)d_out;

    float*        bsum = (float*)d_ws;
    unsigned int* bcnt = (unsigned int*)((char*)d_ws + NBLK * sizeof(float));

    recall_main<<<NBLK, BLK, 0, stream>>>(pred, gt, bsum, bcnt);
    recall_fin<<<1, BLK, 0, stream>>>(bsum, bcnt, out);
}